// Round 3
// baseline (174.259 us; speedup 1.0000x reference)
//
#include <hip/hip_runtime.h>
#include <cstdint>
#include <cstddef>

#define N_DIM 1024
#define D_DIM 512
#define M_DIM 65536
#define NC 6

typedef float f32x4 __attribute__((ext_vector_type(4)));
typedef __bf16 bf16x8 __attribute__((ext_vector_type(8)));

__device__ __forceinline__ float sp_f(float z) {
    return z > 20.f ? z : log1pf(expf(z));
}

// ---------------- ortho loss (reads centroids only) ----------------
__global__ void k_ortho(const float* __restrict__ cent, float* __restrict__ out_ortho) {
    __shared__ float skn[NC * 32];
    __shared__ float ssq[36];
    int t = threadIdx.x; // 64 threads
    if (t < NC) {
        float s = 0.f;
        for (int p = 0; p < 32; ++p) { float v = cent[t * 32 + p]; s += v * v; }
        float inv = 1.f / fmaxf(sqrtf(s), 1e-12f);
        for (int p = 0; p < 32; ++p) skn[t * 32 + p] = cent[t * 32 + p] * inv;
    }
    __syncthreads();
    if (t < 36) {
        int i = t / 6, j = t % 6;
        float g = 0.f;
        for (int p = 0; p < 32; ++p) g += skn[i * 32 + p] * skn[j * 32 + p];
        float d = g - (i == j ? 1.f : 0.f);
        ssq[t] = d * d;
    }
    __syncthreads();
    if (t == 0) {
        float s = 0.f;
        for (int i = 0; i < 36; ++i) s += ssq[i];
        *out_ortho = s / 36.f;
    }
}

// ---------------- stats pass 1: partial (sum, sumsq) -> scratch in d_out ----------------
__global__ void k_stat1(const float* __restrict__ x, float* __restrict__ part) {
    int bid = blockIdx.x;            // 0..511
    int b = bid >> 3, c = bid & 7;   // 8 chunks of 128 rows per b
    int d = threadIdx.x;             // 0..511
    const float* px = x + ((size_t)(b * N_DIM + c * 128)) * D_DIM + d;
    float s = 0.f, q = 0.f;
    for (int i = 0; i < 128; ++i) {
        float v = px[(size_t)i * D_DIM];
        s += v; q += v * v;
    }
    size_t o = ((size_t)bid * D_DIM + d) * 2;
    part[o] = s;
    part[o + 1] = q;
}

// ---------------- stats pass 2: mean + istd into ws ----------------
__global__ void k_stat2(const float* __restrict__ part, float* __restrict__ mean,
                        float* __restrict__ istd) {
    int b = blockIdx.x, d = threadIdx.x;
    float s = 0.f, q = 0.f;
    for (int c = 0; c < 8; ++c) {
        size_t o = (((size_t)(b * 8 + c)) * D_DIM + d) * 2;
        s += part[o]; q += part[o + 1];
    }
    float mu = s * (1.f / (float)N_DIM);
    float var = fmaxf((q - s * mu) * (1.f / (float)(N_DIM - 1)), 0.f);
    float sd = sqrtf(var) + 1e-5f;
    mean[b * D_DIM + d] = mu;
    istd[b * D_DIM + d] = 1.f / sd;
}

// ---------------- MEGA: fused GEMM_A -> row ops -> GEMM_B + epilogue ----------------
__launch_bounds__(256)
__global__ void mega(const float* __restrict__ x,
                     const float* __restrict__ pw, const float* __restrict__ proj_b,
                     const float* __restrict__ ln_g, const float* __restrict__ ln_b,
                     const float* __restrict__ cent,
                     const float* __restrict__ ciw, const float* __restrict__ cib,
                     const float* __restrict__ cow, const float* __restrict__ cob,
                     const float* __restrict__ ga, const float* __restrict__ rlt,
                     const float* __restrict__ sev,
                     const float* __restrict__ mean, const float* __restrict__ istd,
                     float* __restrict__ out, float* __restrict__ ustd_out,
                     float* __restrict__ acc_rout) {
    __shared__ float s_tile[4][16][65];
    __shared__ __align__(16) __bf16 s_h[4][16][40];
    __shared__ float s_asg[64][6];
    __shared__ float s_kn[192], s_cw[192];
    __shared__ float s_pb[32], s_g[32], s_bl[32], s_b2[32];
    __shared__ float s_scal[3];

    int tid = threadIdx.x;
    int wv = tid >> 6, ln = tid & 63;
    int l15 = ln & 15, lg = ln >> 4;

    // ---- per-block setup: CW fold, centroid l2norm, scalars, small vectors
    if (tid < 192) {
        int k = tid >> 5, h = tid & 31;
        float s = 0.f;
        for (int p = 0; p < 32; ++p) s += cent[k * 32 + p] * ciw[h * 544 + 512 + p];
        s_cw[k * 32 + h] = s;
    }
    if (tid >= 192 && tid < 192 + NC) {
        int k = tid - 192;
        float s = 0.f;
        for (int p = 0; p < 32; ++p) { float v = cent[k * 32 + p]; s += v * v; }
        float inv = 1.f / fmaxf(sqrtf(s), 1e-12f);
        for (int p = 0; p < 32; ++p) s_kn[k * 32 + p] = cent[k * 32 + p] * inv;
    }
    if (tid == 198) {
        s_scal[0] = expf(rlt[0]);                 // routing temperature
        s_scal[1] = sp_f(sev[0]);                 // softplus(scale_evidence)
        s_scal[2] = 1.f / (1.f + expf(-ga[0]));   // gate = sigmoid(gate_alpha)
    }
    if (tid < 32) s_pb[tid] = proj_b[tid];
    else if (tid < 64) s_g[tid - 32] = ln_g[tid - 32];
    else if (tid < 96) s_bl[tid - 64] = ln_b[tid - 64];
    else if (tid < 128) s_b2[tid - 96] = cib[tid - 96];
    __syncthreads();

    int row0 = blockIdx.x * 64;
    int b = row0 >> 10;
    int wrow = row0 + wv * 16;
    int myrow = wrow + l15;

    const float* xr = x + (size_t)myrow * D_DIM;
    const float* mb = mean + b * D_DIM;
    const float* ib = istd + b * D_DIM;

    // per-lane weight-row bases: nf 0,1 -> proj rows l15, 16+l15;
    //                            nf 2,3 -> corr_in rows l15, 16+l15 (stride 544)
    const float* wrow_[4];
    wrow_[0] = pw + (size_t)l15 * 512;
    wrow_[1] = pw + (size_t)(16 + l15) * 512;
    wrow_[2] = ciw + (size_t)l15 * 544;
    wrow_[3] = ciw + (size_t)(16 + l15) * 544;

    // ---- Phase A: C[16 x 64] = XN[16 x 512] @ W^T  (hi/lo comp on proj cols)
    f32x4 acc[4];
    #pragma unroll
    for (int nf = 0; nf < 4; ++nf) acc[nf] = (f32x4){0.f, 0.f, 0.f, 0.f};

    for (int ks = 0; ks < 16; ++ks) {
        int k0 = ks * 32 + lg * 8;
        float4 xa = *(const float4*)(xr + k0);
        float4 xb = *(const float4*)(xr + k0 + 4);
        float4 ma = *(const float4*)(mb + k0);
        float4 m2 = *(const float4*)(mb + k0 + 4);
        float4 ia = *(const float4*)(ib + k0);
        float4 i2 = *(const float4*)(ib + k0 + 4);
        float xnf[8];
        xnf[0] = (xa.x - ma.x) * ia.x; xnf[1] = (xa.y - ma.y) * ia.y;
        xnf[2] = (xa.z - ma.z) * ia.z; xnf[3] = (xa.w - ma.w) * ia.w;
        xnf[4] = (xb.x - m2.x) * i2.x; xnf[5] = (xb.y - m2.y) * i2.y;
        xnf[6] = (xb.z - m2.z) * i2.z; xnf[7] = (xb.w - m2.w) * i2.w;
        bf16x8 ah, al;
        #pragma unroll
        for (int j = 0; j < 8; ++j) {
            __bf16 h = (__bf16)xnf[j];
            ah[j] = h;
            al[j] = (__bf16)(xnf[j] - (float)h);
        }
        #pragma unroll
        for (int nf = 0; nf < 4; ++nf) {
            float4 wa = *(const float4*)(wrow_[nf] + k0);
            float4 wb4 = *(const float4*)(wrow_[nf] + k0 + 4);
            float wf[8];
            wf[0] = wa.x; wf[1] = wa.y; wf[2] = wa.z; wf[3] = wa.w;
            wf[4] = wb4.x; wf[5] = wb4.y; wf[6] = wb4.z; wf[7] = wb4.w;
            bf16x8 wh;
            #pragma unroll
            for (int j = 0; j < 8; ++j) wh[j] = (__bf16)wf[j];
            acc[nf] = __builtin_amdgcn_mfma_f32_16x16x32_bf16(ah, wh, acc[nf], 0, 0, 0);
            if (nf < 2) {
                bf16x8 wl;
                #pragma unroll
                for (int j = 0; j < 8; ++j) wl[j] = (__bf16)(wf[j] - (float)wh[j]);
                acc[nf] = __builtin_amdgcn_mfma_f32_16x16x32_bf16(ah, wl, acc[nf], 0, 0, 0);
                acc[nf] = __builtin_amdgcn_mfma_f32_16x16x32_bf16(al, wh, acc[nf], 0, 0, 0);
            }
        }
    }
    #pragma unroll
    for (int nf = 0; nf < 4; ++nf)
        #pragma unroll
        for (int rg = 0; rg < 4; ++rg)
            s_tile[wv][lg * 4 + rg][nf * 16 + l15] = acc[nf][rg];
    __syncthreads();

    // ---- Row ops: LN -> l2norm -> cosine -> softmax -> u_std, h = gelu(...)
    if (ln < 16) {
        int r = ln;
        int grow = wrow + r;
        const float* trow = &s_tile[wv][r][0];
        float P[32]; float mu = 0.f;
        #pragma unroll
        for (int p = 0; p < 32; ++p) { P[p] = trow[p] + s_pb[p]; mu += P[p]; }
        mu *= (1.f / 32.f);
        float var = 0.f;
        #pragma unroll
        for (int p = 0; p < 32; ++p) { float d = P[p] - mu; var += d * d; }
        var *= (1.f / 32.f);
        float rs = rsqrtf(var + 1e-5f);
        float q[32]; float n2 = 0.f;
        #pragma unroll
        for (int p = 0; p < 32; ++p) {
            q[p] = (P[p] - mu) * rs * s_g[p] + s_bl[p];
            n2 += q[p] * q[p];
        }
        float inv = 1.f / fmaxf(sqrtf(n2), 1e-12f);
        float sim[6];
        #pragma unroll
        for (int k = 0; k < 6; ++k) {
            float s = 0.f;
            #pragma unroll
            for (int p = 0; p < 32; ++p) s += q[p] * s_kn[k * 32 + p];
            sim[k] = s * inv;
        }
        float T = s_scal[0];
        float mx = sim[0];
        #pragma unroll
        for (int k = 1; k < 6; ++k) mx = fmaxf(mx, sim[k]);
        float e[6], es = 0.f;
        #pragma unroll
        for (int k = 0; k < 6; ++k) { e[k] = expf((sim[k] - mx) * T); es += e[k]; }
        float einv = 1.f / es;
        float a[6];
        #pragma unroll
        for (int k = 0; k < 6; ++k) { a[k] = e[k] * einv; s_asg[wv * 16 + r][k] = a[k]; }
        // u_std
        float msim = 0.f;
        #pragma unroll
        for (int k = 0; k < 6; ++k) msim += sim[k];
        msim *= (1.f / 6.f);
        float S = 6.f, sevv = s_scal[1];
        #pragma unroll
        for (int k = 0; k < 6; ++k) S += sevv * sp_f((sim[k] - msim) * 5.f);
        ustd_out[grow] = 6.f / S;
        // h = gelu(C2 + b2 + sum_k a_k * CW[k][h])
        #pragma unroll
        for (int h = 0; h < 32; ++h) {
            float v = trow[32 + h] + s_b2[h];
            #pragma unroll
            for (int k = 0; k < 6; ++k) v += a[k] * s_cw[k * 32 + h];
            float g = 0.5f * v * (1.f + erff(v * 0.70710678118654752f));
            s_h[wv][r][h] = (__bf16)g;
        }
    }
    __syncthreads();

    // ---- Phase B: OUT[16 x 512] = H[16 x 32] @ W3[32 x 512], fused epilogue
    bf16x8 ha = *(const bf16x8*)&s_h[wv][l15][lg * 8];
    float gate = s_scal[2];
    for (int nf = 0; nf < 32; ++nf) {
        int col = nf * 16 + l15;
        float4 wa = *(const float4*)(cow + (size_t)col * 32 + lg * 8);
        float4 wb4 = *(const float4*)(cow + (size_t)col * 32 + lg * 8 + 4);
        bf16x8 wb;
        wb[0] = (__bf16)wa.x; wb[1] = (__bf16)wa.y; wb[2] = (__bf16)wa.z; wb[3] = (__bf16)wa.w;
        wb[4] = (__bf16)wb4.x; wb[5] = (__bf16)wb4.y; wb[6] = (__bf16)wb4.z; wb[7] = (__bf16)wb4.w;
        f32x4 z = (f32x4){0.f, 0.f, 0.f, 0.f};
        f32x4 d = __builtin_amdgcn_mfma_f32_16x16x32_bf16(ha, wb, z, 0, 0, 0);
        float bias = cob[col];
        float rsd = 1.f / ib[col];
        #pragma unroll
        for (int rg = 0; rg < 4; ++rg) {
            int row = wrow + lg * 4 + rg;
            float xv = x[(size_t)row * D_DIM + col];
            out[(size_t)row * D_DIM + col] = xv + gate * ((d[rg] + bias) * rsd);
        }
    }

    // ---- routing accumulation (s_asg complete as of the pre-B barrier)
    if (tid < 6) {
        float s = 0.f;
        for (int r = 0; r < 64; ++r) s += s_asg[r][tid];
        atomicAdd(acc_rout + tid, s);
    }
}

// ---------------- latent loss ----------------
__global__ void k5(const float* __restrict__ acc, float* __restrict__ out_latent) {
    if (threadIdx.x == 0) {
        float s = 0.f;
        for (int k = 0; k < 6; ++k) {
            float av = acc[k] * (1.f / (float)M_DIM);
            float d = av - (1.f / 6.f);
            s += d * d;
        }
        *out_latent = s / 6.f;
    }
}

extern "C" void kernel_launch(void* const* d_in, const int* in_sizes, int n_in,
                              void* d_out, int out_size, void* d_ws, size_t ws_size,
                              hipStream_t stream) {
    const float* x      = (const float*)d_in[0];
    const float* proj_w = (const float*)d_in[1];
    const float* proj_b = (const float*)d_in[2];
    const float* ln_g   = (const float*)d_in[3];
    const float* ln_b   = (const float*)d_in[4];
    const float* cent   = (const float*)d_in[5];
    const float* ciw    = (const float*)d_in[6];
    const float* cib    = (const float*)d_in[7];
    const float* cow    = (const float*)d_in[8];
    const float* cob    = (const float*)d_in[9];
    const float* ga     = (const float*)d_in[10];
    const float* rlt    = (const float*)d_in[11];
    const float* sev    = (const float*)d_in[12];

    // ws layout (263 KB): routing acc + mean + istd
    char* ws = (char*)d_ws;
    float* acc  = (float*)(ws + 0);        // 6 f32
    float* mean = (float*)(ws + 1024);     // 64*512 f32 (128 KB)
    float* istd = (float*)(ws + 1024 + 131072);

    // outputs are FLOAT32 (reference output dtype), concatenated flat:
    // out [64,1024,512], u_std [64,1024,1], ortho scalar, latent scalar
    float* outp   = (float*)d_out;
    float* ustd   = outp + (size_t)M_DIM * D_DIM;
    float* ortho  = ustd + M_DIM;
    float* latent = ortho + 1;

    // stats scratch (2 MB) lives at the start of the d_out region; fully
    // consumed by k_stat2 before mega overwrites it (stream-serialized).
    float* part = (float*)d_out;

    hipMemsetAsync(acc, 0, 6 * sizeof(float), stream);
    k_ortho<<<1, 64, 0, stream>>>(cent, ortho);
    k_stat1<<<512, 512, 0, stream>>>(x, part);
    k_stat2<<<64, 512, 0, stream>>>(part, mean, istd);
    mega<<<1024, 256, 0, stream>>>(x, proj_w, proj_b, ln_g, ln_b, cent, ciw, cib,
                                   cow, cob, ga, rlt, sev, mean, istd,
                                   outp, ustd, acc);
    k5<<<1, 64, 0, stream>>>(acc, latent);
}

// Round 4
// 146.016 us; speedup vs baseline: 1.1934x; 1.1934x over previous
//
#include <hip/hip_runtime.h>
#include <cstdint>
#include <cstddef>

#define N_DIM 1024
#define D_DIM 512
#define M_DIM 65536
#define NC 6

typedef float f32x4 __attribute__((ext_vector_type(4)));
typedef __bf16 bf16x8 __attribute__((ext_vector_type(8)));

__device__ __forceinline__ float sp_f(float z) {
    return z > 20.f ? z : log1pf(expf(z));
}

// ---------------- pack: bf16 weights, folded CW, normalized centroids, scalars ----
__global__ void k_pack(const float* __restrict__ pw, const float* __restrict__ ciw,
                       const float* __restrict__ cow, const float* __restrict__ cent,
                       const float* __restrict__ ga, const float* __restrict__ rlt,
                       const float* __restrict__ sev,
                       __bf16* __restrict__ bpa, __bf16* __restrict__ bpl,
                       __bf16* __restrict__ w3p,
                       float* __restrict__ kn, float* __restrict__ cw,
                       float* __restrict__ scal) {
    int bid = blockIdx.x, tid = threadIdx.x;
    if (bid < 128) {
        int i = bid * 256 + tid;          // 0..32767
        int c = i >> 9, k = i & 511;
        float w = (c < 32) ? pw[c * 512 + k] : ciw[(c - 32) * 544 + k];
        __bf16 hi = (__bf16)w;
        bpa[i] = hi;
        if (c < 32) bpl[i] = (__bf16)(w - (float)hi);
    } else if (bid < 192) {
        int j = (bid - 128) * 256 + tid;  // 0..16383
        w3p[j] = (__bf16)cow[j];
    } else {
        if (tid < 192) {                  // CW[k][h] = sum_p cent[k][p]*ciw[h][512+p]
            int k = tid >> 5, h = tid & 31;
            float s = 0.f;
            for (int p = 0; p < 32; ++p) s += cent[k * 32 + p] * ciw[h * 544 + 512 + p];
            cw[k * 32 + h] = s;
        } else if (tid < 192 + NC) {
            int k = tid - 192;
            float s = 0.f;
            for (int p = 0; p < 32; ++p) { float v = cent[k * 32 + p]; s += v * v; }
            float inv = 1.f / fmaxf(sqrtf(s), 1e-12f);
            for (int p = 0; p < 32; ++p) kn[k * 32 + p] = cent[k * 32 + p] * inv;
        } else if (tid == 198) {
            scal[0] = expf(rlt[0]);
            scal[1] = sp_f(sev[0]);
            scal[2] = 1.f / (1.f + expf(-ga[0]));
        }
    }
}

// ---------------- ortho loss ----------------
__global__ void k_ortho(const float* __restrict__ cent, float* __restrict__ out_ortho) {
    __shared__ float skn[NC * 32];
    __shared__ float ssq[36];
    int t = threadIdx.x;
    if (t < NC) {
        float s = 0.f;
        for (int p = 0; p < 32; ++p) { float v = cent[t * 32 + p]; s += v * v; }
        float inv = 1.f / fmaxf(sqrtf(s), 1e-12f);
        for (int p = 0; p < 32; ++p) skn[t * 32 + p] = cent[t * 32 + p] * inv;
    }
    __syncthreads();
    if (t < 36) {
        int i = t / 6, j = t % 6;
        float g = 0.f;
        for (int p = 0; p < 32; ++p) g += skn[i * 32 + p] * skn[j * 32 + p];
        float d = g - (i == j ? 1.f : 0.f);
        ssq[t] = d * d;
    }
    __syncthreads();
    if (t == 0) {
        float s = 0.f;
        for (int i = 0; i < 36; ++i) s += ssq[i];
        *out_ortho = s / 36.f;
    }
}

// ---------------- stats pass 1 ----------------
__global__ void k_stat1(const float* __restrict__ x, float* __restrict__ part) {
    int bid = blockIdx.x;
    int b = bid >> 3, c = bid & 7;
    int d = threadIdx.x;
    const float* px = x + ((size_t)(b * N_DIM + c * 128)) * D_DIM + d;
    float s = 0.f, q = 0.f;
    for (int i = 0; i < 128; ++i) {
        float v = px[(size_t)i * D_DIM];
        s += v; q += v * v;
    }
    size_t o = ((size_t)bid * D_DIM + d) * 2;
    part[o] = s;
    part[o + 1] = q;
}

// ---------------- stats pass 2 ----------------
__global__ void k_stat2(const float* __restrict__ part, float* __restrict__ mean,
                        float* __restrict__ istd, float* __restrict__ stdv) {
    int b = blockIdx.x, d = threadIdx.x;
    float s = 0.f, q = 0.f;
    for (int c = 0; c < 8; ++c) {
        size_t o = (((size_t)(b * 8 + c)) * D_DIM + d) * 2;
        s += part[o]; q += part[o + 1];
    }
    float mu = s * (1.f / (float)N_DIM);
    float var = fmaxf((q - s * mu) * (1.f / (float)(N_DIM - 1)), 0.f);
    float sd = sqrtf(var) + 1e-5f;
    mean[b * D_DIM + d] = mu;
    istd[b * D_DIM + d] = 1.f / sd;
    stdv[b * D_DIM + d] = sd;
}

// ---------------- MEGA: per-wave 16-row tiles, barrier-free ----------------
__launch_bounds__(256)
__global__ void mega(const float* __restrict__ x,
                     const float* __restrict__ proj_b, const float* __restrict__ ln_g,
                     const float* __restrict__ ln_b, const float* __restrict__ cib,
                     const float* __restrict__ cob,
                     const float* __restrict__ mean, const float* __restrict__ istd,
                     const float* __restrict__ stdv,
                     const float* __restrict__ kn, const float* __restrict__ cw,
                     const float* __restrict__ scal,
                     const __bf16* __restrict__ bpa, const __bf16* __restrict__ bpl,
                     const __bf16* __restrict__ w3p,
                     float* __restrict__ out, float* __restrict__ ustd_out,
                     float* __restrict__ rout_part) {
    __shared__ __align__(16) float s_tile[4][16][68];
    __shared__ __align__(16) __bf16 s_h[4][16][40];

    int tid = threadIdx.x;
    int wv = tid >> 6, ln = tid & 63;
    int l15 = ln & 15, lg = ln >> 4;

    int row0 = blockIdx.x * 64;
    int b = row0 >> 10;
    int wrow = row0 + wv * 16;

    const float* xr = x + (size_t)(wrow + l15) * D_DIM;
    const float* mb = mean + b * D_DIM;
    const float* ib = istd + b * D_DIM;

    const __bf16* w0 = bpa + (size_t)l15 * 512;
    const __bf16* w1 = bpa + (size_t)(16 + l15) * 512;
    const __bf16* w2 = bpa + (size_t)(32 + l15) * 512;
    const __bf16* w3 = bpa + (size_t)(48 + l15) * 512;
    const __bf16* wl0 = bpl + (size_t)l15 * 512;
    const __bf16* wl1 = bpl + (size_t)(16 + l15) * 512;

    // ---- Phase A: C[16x64] = XN[16x512] @ W^T, hi/lo compensation on proj cols
    f32x4 a0 = {0.f, 0.f, 0.f, 0.f}, a1 = a0, a2 = a0, a3 = a0;
    #pragma unroll 4
    for (int ks = 0; ks < 16; ++ks) {
        int k0 = ks * 32 + lg * 8;
        float4 xa = *(const float4*)(xr + k0);
        float4 xb = *(const float4*)(xr + k0 + 4);
        float4 ma = *(const float4*)(mb + k0);
        float4 m2 = *(const float4*)(mb + k0 + 4);
        float4 ia = *(const float4*)(ib + k0);
        float4 i2 = *(const float4*)(ib + k0 + 4);
        float xnf[8];
        xnf[0] = (xa.x - ma.x) * ia.x; xnf[1] = (xa.y - ma.y) * ia.y;
        xnf[2] = (xa.z - ma.z) * ia.z; xnf[3] = (xa.w - ma.w) * ia.w;
        xnf[4] = (xb.x - m2.x) * i2.x; xnf[5] = (xb.y - m2.y) * i2.y;
        xnf[6] = (xb.z - m2.z) * i2.z; xnf[7] = (xb.w - m2.w) * i2.w;
        bf16x8 ah, al;
        #pragma unroll
        for (int j = 0; j < 8; ++j) {
            __bf16 h = (__bf16)xnf[j];
            ah[j] = h;
            al[j] = (__bf16)(xnf[j] - (float)h);
        }
        bf16x8 wh0 = *(const bf16x8*)(w0 + k0);
        bf16x8 wh1 = *(const bf16x8*)(w1 + k0);
        a0 = __builtin_amdgcn_mfma_f32_16x16x32_bf16(ah, wh0, a0, 0, 0, 0);
        a0 = __builtin_amdgcn_mfma_f32_16x16x32_bf16(ah, *(const bf16x8*)(wl0 + k0), a0, 0, 0, 0);
        a0 = __builtin_amdgcn_mfma_f32_16x16x32_bf16(al, wh0, a0, 0, 0, 0);
        a1 = __builtin_amdgcn_mfma_f32_16x16x32_bf16(ah, wh1, a1, 0, 0, 0);
        a1 = __builtin_amdgcn_mfma_f32_16x16x32_bf16(ah, *(const bf16x8*)(wl1 + k0), a1, 0, 0, 0);
        a1 = __builtin_amdgcn_mfma_f32_16x16x32_bf16(al, wh1, a1, 0, 0, 0);
        a2 = __builtin_amdgcn_mfma_f32_16x16x32_bf16(ah, *(const bf16x8*)(w2 + k0), a2, 0, 0, 0);
        a3 = __builtin_amdgcn_mfma_f32_16x16x32_bf16(ah, *(const bf16x8*)(w3 + k0), a3, 0, 0, 0);
    }
    #pragma unroll
    for (int rg = 0; rg < 4; ++rg) {
        s_tile[wv][lg * 4 + rg][l15]      = a0[rg];
        s_tile[wv][lg * 4 + rg][16 + l15] = a1[rg];
        s_tile[wv][lg * 4 + rg][32 + l15] = a2[rg];
        s_tile[wv][lg * 4 + rg][48 + l15] = a3[rg];
    }
    // (no barrier: each wave reads only its own LDS region; intra-wave
    //  LDS dependences are ordered by compiler-inserted lgkmcnt waits)

    // ---- Row ops on all 64 lanes: 4-lane groups, r = ln>>2, sub = ln&3
    {
        int r = ln >> 2, sub = ln & 3;
        const float* tr = &s_tile[wv][r][0];
        float4 t0 = *(const float4*)(tr + sub * 8);
        float4 t1 = *(const float4*)(tr + sub * 8 + 4);
        float4 pb0 = *(const float4*)(proj_b + sub * 8);
        float4 pb1 = *(const float4*)(proj_b + sub * 8 + 4);
        float P[8];
        P[0] = t0.x + pb0.x; P[1] = t0.y + pb0.y; P[2] = t0.z + pb0.z; P[3] = t0.w + pb0.w;
        P[4] = t1.x + pb1.x; P[5] = t1.y + pb1.y; P[6] = t1.z + pb1.z; P[7] = t1.w + pb1.w;
        float m = 0.f;
        #pragma unroll
        for (int j = 0; j < 8; ++j) m += P[j];
        m += __shfl_xor(m, 1); m += __shfl_xor(m, 2);
        float mu = m * (1.f / 32.f);
        float v = 0.f;
        #pragma unroll
        for (int j = 0; j < 8; ++j) { float d = P[j] - mu; v += d * d; }
        v += __shfl_xor(v, 1); v += __shfl_xor(v, 2);
        float rs = rsqrtf(v * (1.f / 32.f) + 1e-5f);
        float4 g0 = *(const float4*)(ln_g + sub * 8);
        float4 g1 = *(const float4*)(ln_g + sub * 8 + 4);
        float4 bl0 = *(const float4*)(ln_b + sub * 8);
        float4 bl1 = *(const float4*)(ln_b + sub * 8 + 4);
        float gg[8] = {g0.x, g0.y, g0.z, g0.w, g1.x, g1.y, g1.z, g1.w};
        float bb[8] = {bl0.x, bl0.y, bl0.z, bl0.w, bl1.x, bl1.y, bl1.z, bl1.w};
        float q[8]; float n2 = 0.f;
        #pragma unroll
        for (int j = 0; j < 8; ++j) {
            q[j] = (P[j] - mu) * rs * gg[j] + bb[j];
            n2 += q[j] * q[j];
        }
        n2 += __shfl_xor(n2, 1); n2 += __shfl_xor(n2, 2);
        float inv = 1.f / fmaxf(sqrtf(n2), 1e-12f);
        float sim[6];
        #pragma unroll
        for (int k = 0; k < 6; ++k) {
            const float* kr = kn + k * 32 + sub * 8;
            float4 ka = *(const float4*)(kr);
            float4 kb = *(const float4*)(kr + 4);
            float s = q[0] * ka.x + q[1] * ka.y + q[2] * ka.z + q[3] * ka.w
                    + q[4] * kb.x + q[5] * kb.y + q[6] * kb.z + q[7] * kb.w;
            s += __shfl_xor(s, 1); s += __shfl_xor(s, 2);
            sim[k] = s * inv;
        }
        float T = scal[0], sevv = scal[1];
        float mx = sim[0];
        #pragma unroll
        for (int k = 1; k < 6; ++k) mx = fmaxf(mx, sim[k]);
        float e[6], es = 0.f;
        #pragma unroll
        for (int k = 0; k < 6; ++k) { e[k] = expf((sim[k] - mx) * T); es += e[k]; }
        float einv = 1.f / es;
        float a[6];
        #pragma unroll
        for (int k = 0; k < 6; ++k) a[k] = e[k] * einv;
        // u_std
        float msim = 0.f;
        #pragma unroll
        for (int k = 0; k < 6; ++k) msim += sim[k];
        msim *= (1.f / 6.f);
        float S = 6.f;
        #pragma unroll
        for (int k = 0; k < 6; ++k) S += sevv * sp_f((sim[k] - msim) * 5.f);
        if (sub == 0) ustd_out[wrow + r] = 6.f / S;
        // h = gelu(corr_pre + cib + sum_k a_k*CW[k][:])
        float4 h0 = *(const float4*)(tr + 32 + sub * 8);
        float4 h1 = *(const float4*)(tr + 32 + sub * 8 + 4);
        float4 c0 = *(const float4*)(cib + sub * 8);
        float4 c1 = *(const float4*)(cib + sub * 8 + 4);
        float vh[8] = {h0.x + c0.x, h0.y + c0.y, h0.z + c0.z, h0.w + c0.w,
                       h1.x + c1.x, h1.y + c1.y, h1.z + c1.z, h1.w + c1.w};
        #pragma unroll
        for (int k = 0; k < 6; ++k) {
            const float* cr = cw + k * 32 + sub * 8;
            float4 ca = *(const float4*)(cr);
            float4 cb = *(const float4*)(cr + 4);
            vh[0] += a[k] * ca.x; vh[1] += a[k] * ca.y; vh[2] += a[k] * ca.z; vh[3] += a[k] * ca.w;
            vh[4] += a[k] * cb.x; vh[5] += a[k] * cb.y; vh[6] += a[k] * cb.z; vh[7] += a[k] * cb.w;
        }
        bf16x8 hv;
        #pragma unroll
        for (int j = 0; j < 8; ++j) {
            float gv = 0.5f * vh[j] * (1.f + erff(vh[j] * 0.70710678118654752f));
            hv[j] = (__bf16)gv;
        }
        *(bf16x8*)(&s_h[wv][r][sub * 8]) = hv;
        // routing partial: only sub==0 contributes its row's a[k]
        #pragma unroll
        for (int k = 0; k < 6; ++k) {
            float rv = (sub == 0) ? a[k] : 0.f;
            rv += __shfl_xor(rv, 4); rv += __shfl_xor(rv, 8);
            rv += __shfl_xor(rv, 16); rv += __shfl_xor(rv, 32);
            if (ln == 0) atomicAdd(rout_part + (blockIdx.x & 63) * 6 + k, rv);
        }
    }

    // ---- Phase B: OUT[16x512] = H[16x32] @ W3^T, fused epilogue
    bf16x8 ha = *(const bf16x8*)(&s_h[wv][l15][lg * 8]);
    float gate = scal[2];
    const float* sb = stdv + b * D_DIM;
    for (int nf = 0; nf < 32; ++nf) {
        int col = nf * 16 + l15;
        bf16x8 wb = *(const bf16x8*)(w3p + col * 32 + lg * 8);
        f32x4 z = {0.f, 0.f, 0.f, 0.f};
        f32x4 d = __builtin_amdgcn_mfma_f32_16x16x32_bf16(ha, wb, z, 0, 0, 0);
        float bias = cob[col];
        float rsd = sb[col];
        #pragma unroll
        for (int rg = 0; rg < 4; ++rg) {
            size_t idx = (size_t)(wrow + lg * 4 + rg) * D_DIM + col;
            out[idx] = x[idx] + gate * ((d[rg] + bias) * rsd);
        }
    }
}

// ---------------- latent loss ----------------
__global__ void k5(const float* __restrict__ rp, float* __restrict__ out_latent) {
    __shared__ float sv[6];
    int t = threadIdx.x;
    if (t < 6) {
        float s = 0.f;
        for (int i = 0; i < 64; ++i) s += rp[i * 6 + t];
        sv[t] = s;
    }
    __syncthreads();
    if (t == 0) {
        float s = 0.f;
        for (int k = 0; k < 6; ++k) {
            float av = sv[k] * (1.f / (float)M_DIM) - (1.f / 6.f);
            s += av * av;
        }
        *out_latent = s / 6.f;
    }
}

extern "C" void kernel_launch(void* const* d_in, const int* in_sizes, int n_in,
                              void* d_out, int out_size, void* d_ws, size_t ws_size,
                              hipStream_t stream) {
    const float* x      = (const float*)d_in[0];
    const float* proj_w = (const float*)d_in[1];
    const float* proj_b = (const float*)d_in[2];
    const float* ln_g   = (const float*)d_in[3];
    const float* ln_b   = (const float*)d_in[4];
    const float* cent   = (const float*)d_in[5];
    const float* ciw    = (const float*)d_in[6];
    const float* cib    = (const float*)d_in[7];
    const float* cow    = (const float*)d_in[8];
    const float* cob    = (const float*)d_in[9];
    const float* ga     = (const float*)d_in[10];
    const float* rlt    = (const float*)d_in[11];
    const float* sev    = (const float*)d_in[12];

    // ws layout (~520 KB)
    char* ws = (char*)d_ws;
    float*  rout = (float*)(ws + 0);          // 64*6 f32 (1.5 KB)
    float*  kn   = (float*)(ws + 2048);       // 192 f32
    float*  cwv  = (float*)(ws + 4096);       // 192 f32
    float*  scal = (float*)(ws + 6144);       // 3 f32
    __bf16* bpa  = (__bf16*)(ws + 8192);      // 64*512 bf16 (64 KB)
    __bf16* bpl  = (__bf16*)(ws + 73728);     // 32*512 bf16 (32 KB)
    __bf16* w3p  = (__bf16*)(ws + 106496);    // 512*32 bf16 (32 KB)
    float*  mean = (float*)(ws + 139264);     // 64*512 f32 (128 KB)
    float*  istd = (float*)(ws + 270336);     // 128 KB
    float*  stdv = (float*)(ws + 401408);     // 128 KB

    // outputs: FLOAT32, concatenated flat
    float* outp   = (float*)d_out;
    float* ustd   = outp + (size_t)M_DIM * D_DIM;
    float* ortho  = ustd + M_DIM;
    float* latent = ortho + 1;

    // stats scratch (2 MB) in d_out region; consumed before mega overwrites it
    float* part = (float*)d_out;

    hipMemsetAsync(rout, 0, 64 * 6 * sizeof(float), stream);
    k_pack<<<193, 256, 0, stream>>>(proj_w, ciw, cow, cent, ga, rlt, sev,
                                    bpa, bpl, w3p, kn, cwv, scal);
    k_ortho<<<1, 64, 0, stream>>>(cent, ortho);
    k_stat1<<<512, 512, 0, stream>>>(x, part);
    k_stat2<<<64, 512, 0, stream>>>(part, mean, istd, stdv);
    mega<<<1024, 256, 0, stream>>>(x, proj_b, ln_g, ln_b, cib, cob,
                                   mean, istd, stdv, kn, cwv, scal,
                                   bpa, bpl, w3p, outp, ustd, rout);
    k5<<<1, 64, 0, stream>>>(rout, latent);
}